// Round 6
// baseline (489.165 us; speedup 1.0000x reference)
//
#include <hip/hip_runtime.h>

// EnhancedMemoryStack: B=32768, S=16, D=64. fp32 I/O; bf16 MFMA internally.
//
// Algebra:
//   scores = xhat (Q K^T) xhat^T = xhat M xhat^T, M = Q K^T (128x128) precomputed.
//   z_read = sum_t w[t] vhat[t],  w[t] = sum_s (np[s]/rowsum[s]) e[s][t]  (softmax folded)
//
// R6 structure (R4 math exactly; R5 occupancy plan; fp32 shuffle trees):
//   - Mt and Wv live in GLOBAL memory (d_ws), pre-packed fragment-major so every
//     fragment load is one fully-coalesced global_load_dwordx4 (L2-resident, 48KB total).
//   - LDS = per-wave SY only (8 x 2KB = 16KB/WG) -> occupancy wave-slot-capped:
//     __launch_bounds__(512,6) => up to 24 waves/CU (was 12-16 with 80KB LDS).
//   - All cross-lane reduction trees in fp32 (R5's fp16 packing caused 2.16 absmax).
//
// d_ws: [0..4) counter, [1024..33792) Mt frag-major bf16,
//       [33792..41984) Wv_r, [41984..50176) Wv_i frag-major bf16 (ws_size >= 50176).

typedef __bf16 bf16x8 __attribute__((ext_vector_type(8)));
typedef float  f32x4  __attribute__((ext_vector_type(4)));
typedef float  f4     __attribute__((ext_vector_type(4)));

#define B_TOT   32768
#define GRID_WG 512
#define NWAVES  4096
#define BPW     8
#define LOG2E   1.4426950408889634f
#define EXSC    0.18033688011112042f   // 0.125 * log2(e)

__device__ __forceinline__ unsigned short f2bf(float x) {
  __bf16 h = (__bf16)x;
  return __builtin_bit_cast(unsigned short, h);
}
__device__ __forceinline__ float rcp_f(float x) { return __builtin_amdgcn_rcpf(x); }
__device__ __forceinline__ float ex2_f(float x) { return __builtin_amdgcn_exp2f(x); }
__device__ __forceinline__ float sigm(float x) { return rcp_f(1.0f + ex2_f(-LOG2E * x)); }

__global__ void ems_fin(const unsigned int* __restrict__ c, float* __restrict__ out) {
  if (threadIdx.x == 0) out[0] = (float)(*c) * (1.0f / 32768.0f);
}

// Mt[e2][e] = sum_{E'} Q[e][E'] K[e2][E'], written FRAGMENT-MAJOR:
//   mtf[((n2*4+T)*64 + 16*g + c)*8 + j] = Mt[16*n2+c][32*T+8*g+j]
__global__ void __launch_bounds__(128)
ems_mt(const float* __restrict__ wqr, const float* __restrict__ wqi,
       const float* __restrict__ wkr, const float* __restrict__ wki,
       unsigned short* __restrict__ mtf, unsigned int* __restrict__ cnt)
{
  if (blockIdx.x == 0 && threadIdx.x == 0) *cnt = 0u;
  __shared__ float sK[128];
  const int e2 = (int)blockIdx.x;
  const int e  = (int)threadIdx.x;
  float kv;
  if (e < 64) kv = (e2 < 64) ? wkr[e*64 + e2]      : -wki[e*64 + (e2-64)];
  else        kv = (e2 < 64) ? wki[(e-64)*64 + e2] :  wkr[(e-64)*64 + (e2-64)];
  sK[e] = kv;
  __syncthreads();
  float acc = 0.0f;
  #pragma unroll 8
  for (int Ep = 0; Ep < 64; ++Ep) {
    float q = (e < 64) ? wqr[Ep*64 + e] : -wqi[Ep*64 + (e-64)];
    acc += q * sK[Ep];
  }
  #pragma unroll 8
  for (int Ep = 0; Ep < 64; ++Ep) {
    float q = (e < 64) ? wqi[Ep*64 + e] : wqr[Ep*64 + (e-64)];
    acc += q * sK[64 + Ep];
  }
  int n2 = e2 >> 4, c = e2 & 15;
  int T  = e >> 5, g = (e >> 3) & 3, j = e & 7;
  mtf[(((n2*4 + T)*64) + 16*g + c)*8 + j] = f2bf(acc);
}

// Wv fragment-major: wvf_m[((n*2+t)*64 + 16*g + c)*8 + j] = Wv_m[16n+c][32t+8g+j]
__global__ void __launch_bounds__(512)
ems_wv(const float* __restrict__ wvr, const float* __restrict__ wvi,
       unsigned short* __restrict__ wvf_r, unsigned short* __restrict__ wvf_i)
{
  int idx = (int)blockIdx.x * 512 + (int)threadIdx.x;   // 8 blocks x 512 = 4096
  int e = idx >> 6, d = idx & 63;
  int n = e >> 4, c = e & 15;
  int t = d >> 5, g = (d >> 3) & 3, j = d & 7;
  int dst = (((n*2 + t)*64) + 16*g + c)*8 + j;
  wvf_r[dst] = f2bf(wvr[idx]);
  wvf_i[dst] = f2bf(wvi[idx]);
}

__global__ void __launch_bounds__(512, 6)
ems_main(const float* __restrict__ z_real, const float* __restrict__ z_imag,
         const float* __restrict__ mem,    const float* __restrict__ ptrv,
         const float* __restrict__ ctrl,
         const unsigned short* __restrict__ mtf,
         const unsigned short* __restrict__ wvf_r,
         const unsigned short* __restrict__ wvf_i,
         float* __restrict__ out_zr, float* __restrict__ out_zi,
         float* __restrict__ out_mem, float* __restrict__ out_ptr,
         unsigned int* __restrict__ ws_cnt)
{
  // LDS: per-wave SY only: y[s=16][e2=128] bf16, 16B-chunk swizzle: chunk ^ s
  __shared__ __align__(16) unsigned short lds[8 * 2048];

  const int tid  = (int)threadIdx.x;
  const int lane = tid & 63;
  const int wv   = tid >> 6;
  const int c    = lane & 15;   // MFMA A/B index; slot s for S^T rows
  const int g    = lane >> 4;   // k-chunk group / C-row group

  unsigned short* SY = &lds[wv << 11];

  const f4* mem4 = (const f4*)mem;
  const f4* zr4  = (const f4*)z_real;
  const f4* zi4  = (const f4*)z_imag;
  f4* omem4 = (f4*)out_mem;

  const uint4* mt4 = (const uint4*)mtf;    // fragment (n2*4+T): mt4[((n2*4+T)<<6) + lane]
  const uint4* wr4 = (const uint4*)wvf_r;  // fragment (n*2+t):  wr4[((n*2+t)<<6) + lane]
  const uint4* wi4 = (const uint4*)wvf_i;

  unsigned int active_acc = 0u;
  const int b0 = (int)blockIdx.x * 8 + wv;

  for (int it = 0; it < BPW; ++it) {
    const int b = b0 + it * NWAVES;

    // ---------- global loads ----------
    f4 cm[8], cz[8];
    #pragma unroll
    for (int t4 = 0; t4 < 4; ++t4) {
      int i4 = b*512 + c*32 + t4*8 + g*2;
      cm[2*t4]   = mem4[i4];
      cm[2*t4+1] = mem4[i4+1];
    }
    {
      int zb = b*16 + g*2;
      cz[0] = zr4[zb];   cz[1] = zr4[zb+1];
      cz[2] = zr4[zb+8]; cz[3] = zr4[zb+9];
      cz[4] = zi4[zb];   cz[5] = zi4[zb+1];
      cz[6] = zi4[zb+8]; cz[7] = zi4[zb+9];
    }

    // ---------- gates + pointer update ----------
    float pu = sigm(ctrl[b*3+0]);
    float po = sigm(ctrl[b*3+1]);
    float st = sigm(ctrl[b*3+2]);
    float rt = rcp_f(pu + po + st + 1e-6f);
    pu *= rt; po *= rt; st *= rt;

    float pm = ptrv[b*16 + ((c+15)&15)];
    float pp = ptrv[b*16 + ((c+ 1)&15)];
    float pc = ptrv[b*16 + c];
    float np = pu*pm + po*pp + st*pc;    // new_ptr for slot s=c
    if (g == 0) out_ptr[b*16 + c] = np;
    unsigned long long ball = __ballot(np > 0.1f);
    active_acc += (unsigned int)__popcll(ball & 0xFFFFull);

    // ---------- mem_new (fp32 exact) + xhat fragments ----------
    float om = 1.0f - pu;
    bf16x8 af[4], afn[2];
    #pragma unroll
    for (int t4 = 0; t4 < 4; ++t4) {
      f4 r0 = cm[2*t4]   * om + pu * cz[2*t4];
      f4 r1 = cm[2*t4+1] * om + pu * cz[2*t4+1];
      int i4 = b*512 + c*32 + t4*8 + g*2;
      omem4[i4]   = r0;
      omem4[i4+1] = r1;
      #pragma unroll
      for (int k = 0; k < 4; ++k) {
        af[t4][k]   = (__bf16)r0[k];
        af[t4][4+k] = (__bf16)r1[k];
      }
      if (t4 >= 2) {
        #pragma unroll
        for (int k = 0; k < 4; ++k) {
          afn[t4-2][k]   = (__bf16)(-r0[k]);
          afn[t4-2][4+k] = (__bf16)(-r1[k]);
        }
      }
    }

    // ---------- y = xhat*M (Mt fragments from L2, coalesced) ----------
    // acc[i] = y[s=c][e2 = 16*n2 + 4g + i] -> one packed ds_write_b64 per n2
    #pragma unroll
    for (int n2 = 0; n2 < 8; ++n2) {
      f32x4 acc = {0.f,0.f,0.f,0.f};
      #pragma unroll
      for (int T = 0; T < 4; ++T) {
        bf16x8 am = __builtin_bit_cast(bf16x8, mt4[(((n2 << 2) + T) << 6) + lane]);
        acc = __builtin_amdgcn_mfma_f32_16x16x32_bf16(am, af[T], acc, 0, 0, 0);
      }
      uint2 pk;
      pk.x = (unsigned)f2bf(acc[0]) | ((unsigned)f2bf(acc[1]) << 16);
      pk.y = (unsigned)f2bf(acc[2]) | ((unsigned)f2bf(acc[3]) << 16);
      *(uint2*)&SY[(c << 7) + ((((n2 << 1) + (g >> 1)) ^ c) << 3) + ((g & 1) << 2)] = pk;
    }

    // ---------- S^T = xhat . y^T: lane(c,g) holds S[s=c][t=4g+i] ----------
    f32x4 sc = {0.f,0.f,0.f,0.f};
    #pragma unroll
    for (int T = 0; T < 4; ++T) {
      bf16x8 yb = *(const bf16x8*)&SY[(c << 7) + ((((T << 2) + g) ^ c) << 3)];
      sc = __builtin_amdgcn_mfma_f32_16x16x32_bf16(af[T], yb, sc, 0, 0, 0);
    }

    // ---------- fast softmax + fold np (all fp32) ----------
    float e0 = ex2_f(sc[0] * EXSC);
    float e1 = ex2_f(sc[1] * EXSC);
    float e2v = ex2_f(sc[2] * EXSC);
    float e3 = ex2_f(sc[3] * EXSC);
    float r = (e0 + e1) + (e2v + e3);
    r += __shfl_xor(r, 16, 64);
    r += __shfl_xor(r, 32, 64);          // row-sum over all 16 t
    float u = np * rcp_f(r);             // np for s=c is lane-local
    float v0 = u*e0, v1 = u*e1, v2 = u*e2v, v3 = u*e3;
    #pragma unroll
    for (int d = 1; d <= 8; d <<= 1) {
      v0 += __shfl_xor(v0, d, 64);
      v1 += __shfl_xor(v1, d, 64);
      v2 += __shfl_xor(v2, d, 64);
      v3 += __shfl_xor(v3, d, 64);
    }
    float w4[4] = { v0, v1, v2, v3 };    // w[t = 4g+i]

    // ---------- vhat (Wv fragments from L2) + weighted readout (fp32) ----------
    #pragma unroll
    for (int n = 0; n < 4; ++n) {
      f32x4 ar = {0.f,0.f,0.f,0.f}, ai = {0.f,0.f,0.f,0.f};
      #pragma unroll
      for (int t = 0; t < 2; ++t) {
        int fi4 = (((n << 1) + t) << 6) + lane;
        bf16x8 fr = __builtin_bit_cast(bf16x8, wr4[fi4]);
        bf16x8 fi = __builtin_bit_cast(bf16x8, wi4[fi4]);
        ar = __builtin_amdgcn_mfma_f32_16x16x32_bf16(af[t],   fr, ar, 0,0,0);
        ai = __builtin_amdgcn_mfma_f32_16x16x32_bf16(af[t],   fi, ai, 0,0,0);
        ar = __builtin_amdgcn_mfma_f32_16x16x32_bf16(afn[t],  fi, ar, 0,0,0);
        ai = __builtin_amdgcn_mfma_f32_16x16x32_bf16(af[t+2], fr, ai, 0,0,0);
      }
      float prr = ar[0]*w4[0] + ar[1]*w4[1] + ar[2]*w4[2] + ar[3]*w4[3];
      float pri = ai[0]*w4[0] + ai[1]*w4[1] + ai[2]*w4[2] + ai[3]*w4[3];
      prr += __shfl_xor(prr, 16, 64);
      prr += __shfl_xor(prr, 32, 64);
      pri += __shfl_xor(pri, 16, 64);
      pri += __shfl_xor(pri, 32, 64);
      if (g == 0) out_zr[b*64 + (n << 4) + c] = prr;
      if (g == 1) out_zi[b*64 + (n << 4) + c] = pri;
    }
  }

  // ---------- per-WG count reduction, 1 global atomic per WG ----------
  __syncthreads();                        // all SY use done
  unsigned int* cnt_lds = (unsigned int*)&lds[0];
  if (tid == 0) *cnt_lds = 0u;
  __syncthreads();
  if (lane == 0) atomicAdd(cnt_lds, active_acc);
  __syncthreads();
  if (tid == 0) atomicAdd(ws_cnt, *cnt_lds);
}

extern "C" void kernel_launch(void* const* d_in, const int* in_sizes, int n_in,
                              void* d_out, int out_size, void* d_ws, size_t ws_size,
                              hipStream_t stream) {
  const float* z_real = (const float*)d_in[0];
  const float* z_imag = (const float*)d_in[1];
  const float* memp   = (const float*)d_in[2];
  const float* ptrv   = (const float*)d_in[3];
  const float* ctrl   = (const float*)d_in[4];
  const float* wq_r   = (const float*)d_in[5];
  const float* wq_i   = (const float*)d_in[6];
  const float* wk_r   = (const float*)d_in[7];
  const float* wk_i   = (const float*)d_in[8];
  const float* wv_r   = (const float*)d_in[9];
  const float* wv_i   = (const float*)d_in[10];

  float* out     = (float*)d_out;
  float* out_zr  = out;
  float* out_zi  = out + 2097152;
  float* out_mem = out + 4194304;
  float* out_ptr = out + 71303168;
  float* out_sc  = out + 71827456;

  unsigned int*   cnt   = (unsigned int*)d_ws;
  unsigned short* mtf   = (unsigned short*)((char*)d_ws + 1024);            // 32KB
  unsigned short* wvf_r = (unsigned short*)((char*)d_ws + 33792);           // 8KB
  unsigned short* wvf_i = (unsigned short*)((char*)d_ws + 33792 + 8192);    // 8KB; ws >= 50176

  ems_mt<<<128, 128, 0, stream>>>(wq_r, wq_i, wk_r, wk_i, mtf, cnt);
  ems_wv<<<8, 512, 0, stream>>>(wv_r, wv_i, wvf_r, wvf_i);
  ems_main<<<GRID_WG, 512, 0, stream>>>(z_real, z_imag, memp, ptrv, ctrl,
                                        mtf, wvf_r, wvf_i,
                                        out_zr, out_zi, out_mem, out_ptr, cnt);
  ems_fin<<<1, 64, 0, stream>>>(cnt, out_sc);
}

// Round 7
// 185.167 us; speedup vs baseline: 2.6418x; 2.6418x over previous
//
#include <hip/hip_runtime.h>

// EnhancedMemoryStack: B=32768, S=16, D=64. fp32 I/O; bf16 MFMA internally.
//
// Algebra:
//   scores = xhat (Q K^T) xhat^T = xhat M xhat^T, M = Q K^T (128x128) precomputed.
//   z_read = sum_t w[t] vhat[t],  w[t] = sum_s (np[s]/rowsum[s]) e[s][t]  (softmax folded)
//
// R7 (R4 math bit-for-bit; occupancy push to 3 WG/CU):
//   - Mt in LDS (32KB, proven no-spill path). Wv from GLOBAL frag-major (L1-resident,
//     anti-LICM asm so the 8 loads/batch are not hoisted/held across the loop).
//   - Half-SY: y computed in 2 halves through one 2KB/wave buffer (per-wave DS is
//     in-order; write half -> read 2 K-chunks -> overwrite). LDS 80KB -> 48KB.
//   - 48KB/WG -> 3 WG/CU = 24 waves/CU; grid 768 (=3x256), grid-strided batches.
//   - w-tree via DPP (quad_perm/mirror) adds: bit-identical to shfl_xor 1,2,4,8,
//     zero DS ops.
//
// d_ws: [0..4) counter, [1024..33792) Mt row-major bf16,
//       [33792..41984) Wv_r, [41984..50176) Wv_i frag-major bf16 (ws_size >= 50176).

typedef __bf16 bf16x8 __attribute__((ext_vector_type(8)));
typedef float  f32x4  __attribute__((ext_vector_type(4)));
typedef float  f4     __attribute__((ext_vector_type(4)));

#define B_TOT   32768
#define GRID_WG 768
#define NWAVES  6144            // 768 WG * 8 waves
#define LOG2E   1.4426950408889634f
#define EXSC    0.18033688011112042f   // 0.125 * log2(e)

__device__ __forceinline__ unsigned short f2bf(float x) {
  __bf16 h = (__bf16)x;
  return __builtin_bit_cast(unsigned short, h);
}
__device__ __forceinline__ float rcp_f(float x) { return __builtin_amdgcn_rcpf(x); }
__device__ __forceinline__ float ex2_f(float x) { return __builtin_amdgcn_exp2f(x); }
__device__ __forceinline__ float sigm(float x) { return rcp_f(1.0f + ex2_f(-LOG2E * x)); }

// 16-lane (row) sum, bit-identical to shfl_xor 1,2,4,8 tree, all in VALU via DPP.
__device__ __forceinline__ float dpp_sum16(float v) {
  int x;
  x = __builtin_amdgcn_update_dpp(0, __builtin_bit_cast(int, v), 0xB1, 0xF, 0xF, false); // quad_perm [1,0,3,2] = xor1
  v += __builtin_bit_cast(float, x);
  x = __builtin_amdgcn_update_dpp(0, __builtin_bit_cast(int, v), 0x4E, 0xF, 0xF, false); // quad_perm [2,3,0,1] = xor2
  v += __builtin_bit_cast(float, x);
  x = __builtin_amdgcn_update_dpp(0, __builtin_bit_cast(int, v), 0x141, 0xF, 0xF, false); // row_half_mirror ~ xor4
  v += __builtin_bit_cast(float, x);
  x = __builtin_amdgcn_update_dpp(0, __builtin_bit_cast(int, v), 0x140, 0xF, 0xF, false); // row_mirror ~ xor8
  v += __builtin_bit_cast(float, x);
  return v;
}

__global__ void ems_fin(const unsigned int* __restrict__ c, float* __restrict__ out) {
  if (threadIdx.x == 0) out[0] = (float)(*c) * (1.0f / 32768.0f);
}

// Mt[e2][e] = sum_{E'} Q[e][E'] K[e2][E'] (row-major in d_ws); zeroes the counter.
__global__ void __launch_bounds__(128)
ems_mt(const float* __restrict__ wqr, const float* __restrict__ wqi,
       const float* __restrict__ wkr, const float* __restrict__ wki,
       unsigned short* __restrict__ mt, unsigned int* __restrict__ cnt)
{
  if (blockIdx.x == 0 && threadIdx.x == 0) *cnt = 0u;
  __shared__ float sK[128];
  const int e2 = (int)blockIdx.x;
  const int e  = (int)threadIdx.x;
  float kv;
  if (e < 64) kv = (e2 < 64) ? wkr[e*64 + e2]      : -wki[e*64 + (e2-64)];
  else        kv = (e2 < 64) ? wki[(e-64)*64 + e2] :  wkr[(e-64)*64 + (e2-64)];
  sK[e] = kv;
  __syncthreads();
  float acc = 0.0f;
  #pragma unroll 8
  for (int Ep = 0; Ep < 64; ++Ep) {
    float q = (e < 64) ? wqr[Ep*64 + e] : -wqi[Ep*64 + (e-64)];
    acc += q * sK[Ep];
  }
  #pragma unroll 8
  for (int Ep = 0; Ep < 64; ++Ep) {
    float q = (e < 64) ? wqi[Ep*64 + e] : wqr[Ep*64 + (e-64)];
    acc += q * sK[64 + Ep];
  }
  mt[e2*128 + e] = f2bf(acc);
}

// Wv fragment-major: wvf_m[((n*2+t)*64 + 16*g + c)*8 + j] = Wv_m[16n+c][32t+8g+j]
__global__ void __launch_bounds__(512)
ems_wv(const float* __restrict__ wvr, const float* __restrict__ wvi,
       unsigned short* __restrict__ wvf_r, unsigned short* __restrict__ wvf_i)
{
  int idx = (int)blockIdx.x * 512 + (int)threadIdx.x;   // 8 blocks x 512 = 4096
  int e = idx >> 6, d = idx & 63;
  int n = e >> 4, c = e & 15;
  int t = d >> 5, g = (d >> 3) & 3, j = d & 7;
  int dst = (((n*2 + t)*64) + 16*g + c)*8 + j;
  wvf_r[dst] = f2bf(wvr[idx]);
  wvf_i[dst] = f2bf(wvi[idx]);
}

__global__ void __launch_bounds__(512, 6)
ems_main(const float* __restrict__ z_real, const float* __restrict__ z_imag,
         const float* __restrict__ mem,    const float* __restrict__ ptrv,
         const float* __restrict__ ctrl,
         const unsigned short* __restrict__ mt,
         const unsigned short* __restrict__ wvf_r,
         const unsigned short* __restrict__ wvf_i,
         float* __restrict__ out_zr, float* __restrict__ out_zi,
         float* __restrict__ out_mem, float* __restrict__ out_ptr,
         unsigned int* __restrict__ ws_cnt)
{
  // [0..16384)     Mt bf16 [e2=128][e=128], 16B-chunk swizzle: chunk ^ (e2&15)
  // [16384..24576) per-wave SY half-buffer: y[s=16][64 cols] bf16, chunk ^ (s&7)
  __shared__ __align__(16) unsigned short lds[24576];

  const int tid  = (int)threadIdx.x;

  // stage Mt (uint2 = 4 consecutive e, stays within one swizzle chunk since e%4==0)
  {
    const uint2* mt2 = (const uint2*)mt;
    for (int idx = tid; idx < 4096; idx += 512) {
      int e2 = idx >> 5, e = (idx & 31) << 2;
      *(uint2*)&lds[(e2 << 7) + (((e >> 3) ^ (e2 & 15)) << 3) + (e & 7)] = mt2[idx];
    }
  }
  __syncthreads();

  const int lane = tid & 63;
  const int wv   = tid >> 6;
  const int c    = lane & 15;   // MFMA A/B index; slot s for S^T rows
  const int g    = lane >> 4;   // k-chunk group / C-row group

  unsigned short* SY = &lds[16384 + (wv << 10)];   // 1024 ushorts = 2KB per wave

  const f4* mem4 = (const f4*)mem;
  const f4* zr4  = (const f4*)z_real;
  const f4* zi4  = (const f4*)z_imag;
  f4* omem4 = (f4*)out_mem;

  const uint4* wr4 = (const uint4*)wvf_r;  // fragment (n*2+t): wr4[((n*2+t)<<6) + lane]
  const uint4* wi4 = (const uint4*)wvf_i;

  unsigned int active_acc = 0u;

  for (int b = (int)blockIdx.x * 8 + wv; b < B_TOT; b += NWAVES) {

    // anti-LICM: opaque zero per iteration so Wv loads are not hoisted out of the loop
    int zz = 0;
    asm volatile("" : "+s"(zz));

    // ---------- global loads ----------
    f4 cm[8], cz[8];
    #pragma unroll
    for (int t4 = 0; t4 < 4; ++t4) {
      int i4 = b*512 + c*32 + t4*8 + g*2;
      cm[2*t4]   = mem4[i4];
      cm[2*t4+1] = mem4[i4+1];
    }
    {
      int zb = b*16 + g*2;
      cz[0] = zr4[zb];   cz[1] = zr4[zb+1];
      cz[2] = zr4[zb+8]; cz[3] = zr4[zb+9];
      cz[4] = zi4[zb];   cz[5] = zi4[zb+1];
      cz[6] = zi4[zb+8]; cz[7] = zi4[zb+9];
    }

    // ---------- gates + pointer update ----------
    float pu = sigm(ctrl[b*3+0]);
    float po = sigm(ctrl[b*3+1]);
    float st = sigm(ctrl[b*3+2]);
    float rt = rcp_f(pu + po + st + 1e-6f);
    pu *= rt; po *= rt; st *= rt;

    float pm = ptrv[b*16 + ((c+15)&15)];
    float pp = ptrv[b*16 + ((c+ 1)&15)];
    float pc = ptrv[b*16 + c];
    float np = pu*pm + po*pp + st*pc;    // new_ptr for slot s=c
    if (g == 0) out_ptr[b*16 + c] = np;
    unsigned long long ball = __ballot(np > 0.1f);
    active_acc += (unsigned int)__popcll(ball & 0xFFFFull);

    // ---------- mem_new (fp32 exact) + xhat fragments ----------
    float om = 1.0f - pu;
    bf16x8 af[4], afn[2];
    #pragma unroll
    for (int t4 = 0; t4 < 4; ++t4) {
      f4 r0 = cm[2*t4]   * om + pu * cz[2*t4];
      f4 r1 = cm[2*t4+1] * om + pu * cz[2*t4+1];
      int i4 = b*512 + c*32 + t4*8 + g*2;
      omem4[i4]   = r0;
      omem4[i4+1] = r1;
      #pragma unroll
      for (int k = 0; k < 4; ++k) {
        af[t4][k]   = (__bf16)r0[k];
        af[t4][4+k] = (__bf16)r1[k];
      }
      if (t4 >= 2) {
        #pragma unroll
        for (int k = 0; k < 4; ++k) {
          afn[t4-2][k]   = (__bf16)(-r0[k]);
          afn[t4-2][4+k] = (__bf16)(-r1[k]);
        }
      }
    }

    // ---------- y = xhat*M in 2 halves through the 2KB SY buffer ----------
    // half h covers e2 in [64h, 64h+64) = score K-chunks {2h, 2h+1}
    f32x4 sc = {0.f,0.f,0.f,0.f};
    #pragma unroll
    for (int h = 0; h < 2; ++h) {
      #pragma unroll
      for (int n2 = 0; n2 < 4; ++n2) {
        int e2 = (h << 6) + (n2 << 4) + c;
        f32x4 acc = {0.f,0.f,0.f,0.f};
        #pragma unroll
        for (int T = 0; T < 4; ++T) {
          bf16x8 am = *(const bf16x8*)&lds[(e2 << 7) + ((((T << 2) + g) ^ c) << 3)];
          acc = __builtin_amdgcn_mfma_f32_16x16x32_bf16(am, af[T], acc, 0, 0, 0);
        }
        uint2 pk;
        pk.x = (unsigned)f2bf(acc[0]) | ((unsigned)f2bf(acc[1]) << 16);
        pk.y = (unsigned)f2bf(acc[2]) | ((unsigned)f2bf(acc[3]) << 16);
        // local col = 16*n2 + 4g + i; chunk = 2*n2 + (g>>1), dword-half (g&1)
        *(uint2*)&SY[(c << 6) + ((((n2 << 1) + (g >> 1)) ^ (c & 7)) << 3) + ((g & 1) << 2)] = pk;
      }
      #pragma unroll
      for (int Tp = 0; Tp < 2; ++Tp) {
        bf16x8 yb = *(const bf16x8*)&SY[(c << 6) + ((((Tp << 2) + g) ^ (c & 7)) << 3)];
        sc = __builtin_amdgcn_mfma_f32_16x16x32_bf16(af[(h << 1) + Tp], yb, sc, 0, 0, 0);
      }
    }

    // ---------- fast softmax + fold np (fp32; w-tree via DPP) ----------
    float e0 = ex2_f(sc[0] * EXSC);
    float e1 = ex2_f(sc[1] * EXSC);
    float e2v = ex2_f(sc[2] * EXSC);
    float e3 = ex2_f(sc[3] * EXSC);
    float r = (e0 + e1) + (e2v + e3);
    r += __shfl_xor(r, 16, 64);
    r += __shfl_xor(r, 32, 64);          // row-sum over all 16 t
    float u = np * rcp_f(r);             // np for s=c is lane-local
    float w4[4];
    w4[0] = dpp_sum16(u * e0);
    w4[1] = dpp_sum16(u * e1);
    w4[2] = dpp_sum16(u * e2v);
    w4[3] = dpp_sum16(u * e3);           // w[t = 4g+i]

    // ---------- vhat (Wv frags from global/L1) + weighted readout ----------
    #pragma unroll
    for (int n = 0; n < 4; ++n) {
      f32x4 ar = {0.f,0.f,0.f,0.f}, ai = {0.f,0.f,0.f,0.f};
      #pragma unroll
      for (int t = 0; t < 2; ++t) {
        int fi4 = (((n << 1) + t) << 6) + lane + zz;
        bf16x8 fr = __builtin_bit_cast(bf16x8, wr4[fi4]);
        bf16x8 fi = __builtin_bit_cast(bf16x8, wi4[fi4]);
        ar = __builtin_amdgcn_mfma_f32_16x16x32_bf16(af[t],   fr, ar, 0,0,0);
        ai = __builtin_amdgcn_mfma_f32_16x16x32_bf16(af[t],   fi, ai, 0,0,0);
        ar = __builtin_amdgcn_mfma_f32_16x16x32_bf16(afn[t],  fi, ar, 0,0,0);
        ai = __builtin_amdgcn_mfma_f32_16x16x32_bf16(af[t+2], fr, ai, 0,0,0);
      }
      float prr = ar[0]*w4[0] + ar[1]*w4[1] + ar[2]*w4[2] + ar[3]*w4[3];
      float pri = ai[0]*w4[0] + ai[1]*w4[1] + ai[2]*w4[2] + ai[3]*w4[3];
      prr += __shfl_xor(prr, 16, 64);
      prr += __shfl_xor(prr, 32, 64);
      pri += __shfl_xor(pri, 16, 64);
      pri += __shfl_xor(pri, 32, 64);
      if (g == 0) out_zr[b*64 + (n << 4) + c] = prr;
      if (g == 1) out_zi[b*64 + (n << 4) + c] = pri;
    }
  }

  // ---------- per-WG count reduction, 1 global atomic per WG ----------
  __syncthreads();                        // all SY use done
  unsigned int* cnt_lds = (unsigned int*)&lds[16384];
  if (tid == 0) *cnt_lds = 0u;
  __syncthreads();
  if (lane == 0) atomicAdd(cnt_lds, active_acc);
  __syncthreads();
  if (tid == 0) atomicAdd(ws_cnt, *cnt_lds);
}

extern "C" void kernel_launch(void* const* d_in, const int* in_sizes, int n_in,
                              void* d_out, int out_size, void* d_ws, size_t ws_size,
                              hipStream_t stream) {
  const float* z_real = (const float*)d_in[0];
  const float* z_imag = (const float*)d_in[1];
  const float* memp   = (const float*)d_in[2];
  const float* ptrv   = (const float*)d_in[3];
  const float* ctrl   = (const float*)d_in[4];
  const float* wq_r   = (const float*)d_in[5];
  const float* wq_i   = (const float*)d_in[6];
  const float* wk_r   = (const float*)d_in[7];
  const float* wk_i   = (const float*)d_in[8];
  const float* wv_r   = (const float*)d_in[9];
  const float* wv_i   = (const float*)d_in[10];

  float* out     = (float*)d_out;
  float* out_zr  = out;
  float* out_zi  = out + 2097152;
  float* out_mem = out + 4194304;
  float* out_ptr = out + 71303168;
  float* out_sc  = out + 71827456;

  unsigned int*   cnt   = (unsigned int*)d_ws;
  unsigned short* mtp   = (unsigned short*)((char*)d_ws + 1024);            // 32KB row-major
  unsigned short* wvf_r = (unsigned short*)((char*)d_ws + 33792);           // 8KB frag-major
  unsigned short* wvf_i = (unsigned short*)((char*)d_ws + 33792 + 8192);    // 8KB; ws >= 50176

  ems_mt<<<128, 128, 0, stream>>>(wq_r, wq_i, wk_r, wk_i, mtp, cnt);
  ems_wv<<<8, 512, 0, stream>>>(wv_r, wv_i, wvf_r, wvf_i);
  ems_main<<<GRID_WG, 512, 0, stream>>>(z_real, z_imag, memp, ptrv, ctrl,
                                        mtp, wvf_r, wvf_i,
                                        out_zr, out_zi, out_mem, out_ptr, cnt);
  ems_fin<<<1, 64, 0, stream>>>(cnt, out_sc);
}